// Round 8
// baseline (188.159 us; speedup 1.0000x reference)
//
#include <hip/hip_runtime.h>
#include <cstdint>
#include <cstddef>

#define B_ 8
#define C_ 32
#define W_ 32
#define H_ 32
#define A_ 6
#define NCLS 14
#define M_ 64
#define HARD_NUM 256
#define LAM_HNM 0.2f
#define LAM_NOOBJ 0.001f

#define NCH 17
#define NPOS (B_*C_*W_*H_*A_)
#define TOTAL (NPOS*NCH)          // 26,738,688 floats

#define KSHIFT 21                 // key>>21 -> 11-bit coarse bin id
#define HB0 1532                  // bin of x=1.0
#define NHB 512                   // window [HB0, HB0+512): x in [1.0, inf)
#define HSLOTS3 (NHB*8)           // 4096 u32 LDS slots (7 class pairs + pad)
#define SUBBITS 11
#define NBIN_F (1<<SUBBITS)       // 2048 fine sub-bins
#define KA_BLOCKS 512

// ws layout (nothing needs pre-zeroing by a separate kernel)
#define OFF_FACC   0              // f32[16]: 0=cl_pos 1=cl_neg 2=reg 3=regu
#define OFF_UACC   64             // u32[16]: 0=pos_count, 1..14=per-class hn counts
#define OFF_BSTAR  128            // i32[16]
#define OFF_CNTAB  192            // u32[16]
#define OFF_SUMAB  256            // f32[16]
#define OFF_HNP    320            // f32[16] per-class hn partial
#define OFF_DONE   384            // u32 arrival counter
#define OFF_RSUM   512            // f32[512] per-block regu partials
#define OFF_NBLK   2560           // u32[512] per-block candidate counts
#define OFF_FINE   8192           // u64[14*2048] = 229376
#define OFF_PART   262144         // u32[8 planes][512 blk][512 bin] = 8 MB
#define OFF_CAND   (262144 + 8*KA_BLOCKS*NHB*4)   // 8,650,752

__device__ __forceinline__ float spf(float x) {   // fast softplus
    return fmaxf(x, 0.0f) + __logf(1.0f + __expf(-fabsf(x)));
}
__device__ __forceinline__ float sp(float x) {    // precise (proposal path)
    return fmaxf(x, 0.0f) + log1pf(__expf(-fabsf(x)));
}

// ==== K1: stream pm once — regu partials, windowed hist (transposed planes),
//          candidate compaction; block 0 also folds the 3072 proposals =======
__global__ __launch_bounds__(1024)
void k1_stream(const float* __restrict__ pm, const int* __restrict__ pidx,
               const float* __restrict__ preg,
               unsigned* __restrict__ partials_t, unsigned* __restrict__ cand,
               unsigned* __restrict__ nblk, float* __restrict__ rsum,
               float* __restrict__ facc, unsigned* __restrict__ uacc, int seg) {
    __shared__ unsigned hist[HSLOTS3];
    __shared__ unsigned lds_ctr;
    __shared__ float wsum[16];
    __shared__ float p_clp, p_cln, p_rg;
    __shared__ unsigned p_pos, p_hn[14];
    for (int i = threadIdx.x; i < HSLOTS3; i += 1024) hist[i] = 0;
    if (threadIdx.x == 0) lds_ctr = 0;
    __syncthreads();
    unsigned* gcand = cand + (size_t)blockIdx.x * seg;
    int lane = threadIdx.x & 63;
    int tid = blockIdx.x * blockDim.x + threadIdx.x;
    int nth = gridDim.x * blockDim.x;
    float racc = 0.0f;
    for (int i = tid; i < TOTAL / 4; i += nth) {
        float4 v = reinterpret_cast<const float4*>(pm)[i];
        float vv[4] = {v.x, v.y, v.z, v.w};
        int ch = (i * 4) % NCH;
#pragma unroll
        for (int j = 0; j < 4; ++j) {
            float x = vv[j];
            racc += spf(x);
            bool q = (ch >= 3) && (x >= 1.0f);
            unsigned ut = __float_as_uint(x) & 0xFFFFFFF0u;  // truncated key base
            if (q) {
                unsigned bin = (ut | 0x80000000u) >> KSHIFT;  // x>0: key = u|sign
                unsigned wb = bin - HB0;
                if (wb > NHB - 1) wb = NHB - 1;
                int cm3 = ch - 3;
                atomicAdd(&hist[wb * 8 + (cm3 >> 1)], (cm3 & 1) ? 0x10000u : 1u);
            }
            unsigned long long mb = __ballot(q);
            if (mb) {
                unsigned base = 0;
                int leader = __ffsll((unsigned long long)mb) - 1;
                if (lane == leader)
                    base = atomicAdd(&lds_ctr, (unsigned)__popcll(mb));
                base = __shfl(base, leader, 64);
                if (q) {
                    unsigned off = (unsigned)__popcll(mb & ((1ull << lane) - 1ull));
                    unsigned idx = base + off;
                    if ((int)idx < seg) gcand[idx] = ut | (unsigned)(ch - 3);
                }
            }
            ch = (ch == NCH - 1) ? 0 : ch + 1;
        }
    }
    __syncthreads();
    // transposed plane-major partial write: [pair][block][bin]
    for (int p = 0; p < 8; ++p)
        for (int b = threadIdx.x; b < NHB; b += 1024)
            partials_t[(size_t)p * KA_BLOCKS * NHB + (size_t)blockIdx.x * NHB + b]
                = hist[b * 8 + p];
    if (threadIdx.x == 0)
        nblk[blockIdx.x] = (lds_ctr < (unsigned)seg) ? lds_ctr : (unsigned)seg;
    // regu partial -> rsum[block] (no atomics, no pre-zero needed)
    for (int off = 32; off; off >>= 1) racc += __shfl_down(racc, off, 64);
    int wid = threadIdx.x >> 6;
    if (lane == 0) wsum[wid] = racc;
    __syncthreads();
    if (threadIdx.x == 0) {
        float s = 0.0f;
        for (int w = 0; w < 16; ++w) s += wsum[w];
        rsum[blockIdx.x] = s;
    }
    // ---- block 0: proposals (3072 gathers) into LDS, then plain stores ----
    if (blockIdx.x == 0) {
        if (threadIdx.x == 0) { p_clp = 0; p_cln = 0; p_rg = 0; p_pos = 0; }
        if (threadIdx.x < 14) p_hn[threadIdx.x] = 0;
        __syncthreads();
        for (int t = threadIdx.x; t < B_ * A_ * M_; t += 1024) {
            int b = t / (A_ * M_);
            int a = (t / M_) % A_;
            const int* q = pidx + (size_t)t * 4;
            int c = q[0], w = q[1], h = q[2], lab = q[3];
            if (lab == -100) continue;
            if (lab < 0) { atomicAdd(&p_hn[-1 - lab], 1u); continue; }
            atomicAdd(&p_pos, 1u);
            const float* v = pm + (size_t)((((b * C_ + c) * W_ + w) * H_ + h) * A_ + a) * NCH;
            float clp = 0.0f, cln = 0.0f;
#pragma unroll
            for (int j = 0; j < NCLS; ++j) {
                float lg = v[3 + j];
                if (j == lab) clp = sp(-lg);
                else          cln += sp(lg);
            }
            float rg = 0.0f;
            const float* pr = preg + (size_t)t * 3;
#pragma unroll
            for (int j = 0; j < 3; ++j) {
                float d = tanhf(v[j]) - pr[j];
                float ad = fabsf(d);
                rg += (ad < 1.0f) ? 0.5f * d * d : ad - 0.5f;
            }
            atomicAdd(&p_clp, clp);
            atomicAdd(&p_cln, cln);
            atomicAdd(&p_rg, rg);
        }
        __syncthreads();
        if (threadIdx.x == 0) {
            facc[0] = p_clp; facc[1] = p_cln; facc[2] = p_rg;
            uacc[0] = p_pos;
        }
        if (threadIdx.x < 14) uacc[1 + threadIdx.x] = p_hn[threadIdx.x];
    }
}

// ==== K2: per-class boundary from planes + zero fine/sumab; block14 = regu ===
__global__ __launch_bounds__(256)
void k2_bound(const unsigned* __restrict__ partials_t,
              const float* __restrict__ rsum, const unsigned* __restrict__ uacc,
              int* __restrict__ bstar, unsigned* __restrict__ cntab,
              float* __restrict__ sumab, float* __restrict__ facc,
              unsigned long long* __restrict__ fine, unsigned* __restrict__ done) {
    int t = threadIdx.x;
    __shared__ unsigned cnt[NHB];
    __shared__ float ws2[256];
    if (blockIdx.x == 14) {                     // regu total + done reset
        if (t == 0) *done = 0u;
        ws2[t] = rsum[t] + rsum[t + 256];
        __syncthreads();
        for (int o = 128; o; o >>= 1) { if (t < o) ws2[t] += ws2[t + o]; __syncthreads(); }
        if (t == 0) facc[3] = ws2[0];
        return;
    }
    int cls = blockIdx.x;
    unsigned long long* fc = fine + (size_t)cls * NBIN_F;
    for (int i = t; i < NBIN_F; i += 256) fc[i] = 0ull;
    if (t == 0) sumab[cls] = 0.0f;
    unsigned k = uacc[1 + cls] * HARD_NUM;
    if (k == 0) { if (t == 0) bstar[cls] = -2; return; }
    const unsigned* plane = partials_t + (size_t)(cls >> 1) * KA_BLOCKS * NHB;
    int half = cls & 1;
    unsigned c0 = 0, c1 = 0;
    for (int blk = 0; blk < KA_BLOCKS; ++blk) {
        unsigned v0 = plane[(size_t)blk * NHB + t];
        unsigned v1 = plane[(size_t)blk * NHB + t + 256];
        c0 += half ? (v0 >> 16) : (v0 & 0xFFFFu);
        c1 += half ? (v1 >> 16) : (v1 & 0xFFFFu);
    }
    cnt[t] = c0; cnt[t + 256] = c1;
    __syncthreads();
    if (t == 0) {
        unsigned cum = 0; int bb = -1;
        for (int b = NHB - 1; b >= 0; --b) {
            unsigned c = cnt[b];
            if (cum + c >= k) { bb = b; break; }
            cum += c;
        }
        bstar[cls] = bb;            // -1 => select all candidates (fallback)
        cntab[cls] = cum;
    }
}

// ==== K3: candidate pass — sum above boundary + fine hist of boundary bin ====
__global__ __launch_bounds__(256)
void k3_cand(const unsigned* __restrict__ cand, const unsigned* __restrict__ nblk,
             const int* __restrict__ bstar, unsigned long long* __restrict__ fine,
             float* __restrict__ sumab, int seg) {
    __shared__ float csum[16];
    __shared__ int bst[16];
    int t = threadIdx.x;
    if (t < 16) { csum[t] = 0.0f; bst[t] = (t < 14) ? bstar[t] : -2; }
    __syncthreads();
    const unsigned* gcand = cand + (size_t)blockIdx.x * seg;
    unsigned n = nblk[blockIdx.x];
    for (unsigned i = t; i < n; i += blockDim.x) {
        unsigned e = gcand[i];
        int cls = (int)(e & 15u);
        int b = bst[cls];
        if (b == -2) continue;
        unsigned ut = e & 0xFFFFFFF0u;
        unsigned key = ut | 0x80000000u;
        unsigned wb = (key >> KSHIFT) - HB0;
        if (wb > NHB - 1) wb = NHB - 1;
        float x = __uint_as_float(ut | 0x8u);
        if (b == -1 || (int)wb > b) {
            atomicAdd(&csum[cls], spf(x));
        } else if ((int)wb == b) {
            unsigned sub = (key >> (KSHIFT - SUBBITS)) & (NBIN_F - 1);
            unsigned long long pk = (1ull << 43)
                | (unsigned long long)(spf(x) * 262144.0f + 0.5f);
            atomicAdd(&fine[(size_t)cls * NBIN_F + sub], pk);
        }
    }
    __syncthreads();
    if (t < 14 && csum[t] != 0.0f) atomicAdd(&sumab[t], csum[t]);
}

// ==== K4: per-class resolve + last-block final combine =======================
__global__ __launch_bounds__(256)
void k4_resolve(const unsigned long long* __restrict__ fine,
                const unsigned* __restrict__ uacc, const int* __restrict__ bstar,
                const unsigned* __restrict__ cntab, const float* __restrict__ sumab,
                const float* __restrict__ facc, float* __restrict__ hnp,
                unsigned* __restrict__ done, float* __restrict__ out) {
    int cls = blockIdx.x, t = threadIdx.x;
    __shared__ unsigned ck[256];
    __shared__ float cs[256];
    __shared__ int lastflag;
    unsigned k = uacc[1 + cls] * HARD_NUM;
    if (k == 0) {
        if (t == 0) hnp[cls] = 0.0f;
    } else {
        int b = bstar[cls];
        if (b == -1) {
            if (t == 0) hnp[cls] = sumab[cls];
        } else {
            unsigned r = k - cntab[cls];          // >= 1 by construction
            const unsigned long long* fc = fine + (size_t)cls * NBIN_F;
            unsigned lc = 0; float ls = 0.0f;
            for (int j = 0; j < NBIN_F / 256; ++j) {
                unsigned long long v = fc[t * (NBIN_F / 256) + j];
                lc += (unsigned)(v >> 43);
                ls += (float)(v & ((1ull << 43) - 1)) * (1.0f / 262144.0f);
            }
            ck[t] = lc; cs[t] = ls;
            __syncthreads();
            if (t == 0) {
                unsigned cum = 0; float sa = sumab[cls];
                for (int ch = 255; ch >= 0; --ch) {
                    if (cum + ck[ch] >= r) {
                        unsigned c2 = cum;
                        for (int j = NBIN_F / 256 - 1; j >= 0; --j) {
                            unsigned long long v = fc[ch * (NBIN_F / 256) + j];
                            unsigned c = (unsigned)(v >> 43);
                            float s = (float)(v & ((1ull << 43) - 1)) * (1.0f / 262144.0f);
                            if (c2 + c >= r) {
                                unsigned rem = r - c2;
                                if (c > 0) sa += (float)rem * (s / (float)c);
                                break;
                            }
                            c2 += c; sa += s;
                        }
                        break;
                    }
                    cum += ck[ch]; sa += cs[ch];
                }
                hnp[cls] = sa;
            }
        }
    }
    __syncthreads();
    if (t == 0) {
        __threadfence();
        unsigned ticket = atomicAdd(done, 1u);
        lastflag = (ticket == NCLS - 1) ? 1 : 0;
    }
    __syncthreads();
    if (lastflag && t == 0) {
        __threadfence();
        float hn_sum = 0.0f; unsigned totk = 0;
        for (int j = 0; j < NCLS; ++j) { hn_sum += hnp[j]; totk += uacc[1 + j]; }
        totk *= HARD_NUM;
        float P = fmaxf((float)uacc[0], 1.0f);
        float hn = (totk > 0) ? (LAM_HNM * hn_sum / (float)totk) : 0.0f;
        out[0] = facc[0] / P
               + facc[1] / (P * (float)((NCLS - 1) * (NCLS - 1)))
               + hn
               + LAM_NOOBJ * facc[3] / (float)TOTAL
               + facc[2] / (3.0f * P);
    }
}

extern "C" void kernel_launch(void* const* d_in, const int* in_sizes, int n_in,
                              void* d_out, int out_size, void* d_ws, size_t ws_size,
                              hipStream_t stream) {
    const float* pm   = (const float*)d_in[0];
    const int*   pidx = (const int*)d_in[1];
    const float* preg = (const float*)d_in[2];
    float* out = (float*)d_out;
    char* ws = (char*)d_ws;

    float*    facc  = (float*)(ws + OFF_FACC);
    unsigned* uacc  = (unsigned*)(ws + OFF_UACC);
    int*      bstar = (int*)(ws + OFF_BSTAR);
    unsigned* cntab = (unsigned*)(ws + OFF_CNTAB);
    float*    sumab = (float*)(ws + OFF_SUMAB);
    float*    hnp   = (float*)(ws + OFF_HNP);
    unsigned* done  = (unsigned*)(ws + OFF_DONE);
    float*    rsum  = (float*)(ws + OFF_RSUM);
    unsigned* nblk  = (unsigned*)(ws + OFF_NBLK);
    unsigned long long* fine = (unsigned long long*)(ws + OFF_FINE);
    unsigned* partials_t = (unsigned*)(ws + OFF_PART);
    unsigned* cand = (unsigned*)(ws + OFF_CAND);

    long long remain = (long long)ws_size - (long long)OFF_CAND;
    int seg = (int)(remain / (KA_BLOCKS * 4));
    if (seg > 32768) seg = 32768;
    seg &= ~63;
    if (seg < 1024) seg = 1024;

    k1_stream <<<KA_BLOCKS, 1024, 0, stream>>>(pm, pidx, preg, partials_t, cand,
                                               nblk, rsum, facc, uacc, seg);
    k2_bound  <<<NCLS + 1, 256, 0, stream>>>(partials_t, rsum, uacc, bstar, cntab,
                                             sumab, facc, fine, done);
    k3_cand   <<<KA_BLOCKS, 256, 0, stream>>>(cand, nblk, bstar, fine, sumab, seg);
    k4_resolve<<<NCLS, 256, 0, stream>>>(fine, uacc, bstar, cntab, sumab, facc,
                                         hnp, done, out);
}

// Round 9
// 163.507 us; speedup vs baseline: 1.1508x; 1.1508x over previous
//
#include <hip/hip_runtime.h>
#include <cstdint>
#include <cstddef>

#define B_ 8
#define C_ 32
#define W_ 32
#define H_ 32
#define A_ 6
#define NCLS 14
#define M_ 64
#define HARD_NUM 256
#define LAM_HNM 0.2f
#define LAM_NOOBJ 0.001f

#define NCH 17
#define NPOS (B_*C_*W_*H_*A_)
#define TOTAL (NPOS*NCH)          // 26,738,688 floats

#define KSHIFT 21                 // key>>21 -> 11-bit coarse bin id
#define HB0 1532                  // bin of x=1.0
#define NHB 512                   // window [HB0,HB0+512): x in [1.0, inf)
#define HSLOTS3 (NHB*8)           // 4096 u32 LDS slots (7 class pairs + pad)
#define SUBBITS 11
#define NBIN_F (1<<SUBBITS)       // 2048 fine sub-bins
#define KA_BLOCKS 512
#define WPB 16                    // waves per block (1024 threads)
#define NSEG (KA_BLOCKS*WPB)      // 8192 wave segments

// ws layout (nothing needs pre-zeroing across calls)
#define OFF_FACC   0              // f32[16]
#define OFF_UACC   64             // u32[16]
#define OFF_BSTAR  128            // i32[16]
#define OFF_CNTAB  192            // u32[16]
#define OFF_SUMAB  256            // f32[16]
#define OFF_HNP    320            // f32[16]
#define OFF_DONE   384            // u32
#define OFF_RSUM   512            // f32[512]
#define OFF_NBLK   4096           // u32[NSEG] = 32 KB
#define OFF_FINE   36864          // u64[14*2048] = 229376
#define OFF_MERGED 266240         // u32[4][512*16] = 128 KB
#define OFF_PART   397312         // u32[512][4096] = 8 MB
#define OFF_CAND   (397312 + KA_BLOCKS*HSLOTS3*4)   // 8,785,920

__device__ __forceinline__ float spf(float x) {   // fast softplus
    return fmaxf(x, 0.0f) + __logf(1.0f + __expf(-fabsf(x)));
}
__device__ __forceinline__ float sp(float x) {    // precise (proposal path)
    return fmaxf(x, 0.0f) + log1pf(__expf(-fabsf(x)));
}

// ==== K1: single stream — regu partials, windowed hist, reg-based wave
//          compaction into per-wave segments; block 0 folds proposals ========
__global__ __launch_bounds__(1024)
void k1_stream(const float* __restrict__ pm, const int* __restrict__ pidx,
               const float* __restrict__ preg,
               unsigned* __restrict__ partials, unsigned* __restrict__ cand,
               unsigned* __restrict__ nblk, float* __restrict__ rsum,
               float* __restrict__ facc, unsigned* __restrict__ uacc,
               int seg_w) {
    __shared__ unsigned hist[HSLOTS3];
    __shared__ float wsum[WPB];
    __shared__ float p_clp, p_cln, p_rg;
    __shared__ unsigned p_pos, p_hn[14];
    for (int i = threadIdx.x; i < HSLOTS3; i += 1024) hist[i] = 0;
    __syncthreads();
    int lane = threadIdx.x & 63;
    int wid = threadIdx.x >> 6;
    unsigned wseg = blockIdx.x * WPB + wid;
    unsigned* gc = cand + (size_t)wseg * seg_w;
    unsigned wcount = 0;          // wave-uniform register counter
    float racc = 0.0f;
    int tid = blockIdx.x * blockDim.x + threadIdx.x;
    int nth = gridDim.x * blockDim.x;
    const int n4 = TOTAL / 4;
    int i = tid;
    if (i < n4) {
        float4 v = reinterpret_cast<const float4*>(pm)[i];
        while (true) {
            int inext = i + nth;
            float4 vn;
            if (inext < n4) vn = reinterpret_cast<const float4*>(pm)[inext];
            float vv[4] = {v.x, v.y, v.z, v.w};
            int ch = (i * 4) % NCH;
#pragma unroll
            for (int j = 0; j < 4; ++j) {
                float x = vv[j];
                racc += spf(x);
                bool q = (ch >= 3) && (x >= 1.0f);
                unsigned long long mb = __ballot(q);
                if (q) {
                    unsigned ut = __float_as_uint(x) & 0xFFFFFFF0u;
                    unsigned bin = (ut | 0x80000000u) >> KSHIFT;
                    unsigned wb = bin - HB0;
                    if (wb > NHB - 1) wb = NHB - 1;
                    int cm3 = ch - 3;
                    atomicAdd(&hist[wb * 8 + (cm3 >> 1)], (cm3 & 1) ? 0x10000u : 1u);
                    unsigned idx = wcount +
                        (unsigned)__popcll(mb & ((1ull << lane) - 1ull));
                    if (idx < (unsigned)seg_w) gc[idx] = ut | (unsigned)cm3;
                }
                wcount += (unsigned)__popcll(mb);
                ch = (ch == NCH - 1) ? 0 : ch + 1;
            }
            if (inext >= n4) break;
            v = vn; i = inext;
        }
    }
    if (lane == 0)
        nblk[wseg] = (wcount < (unsigned)seg_w) ? wcount : (unsigned)seg_w;
    __syncthreads();
    unsigned* dst = partials + (size_t)blockIdx.x * HSLOTS3;
    for (int s = threadIdx.x; s < HSLOTS3; s += 1024) dst[s] = hist[s];
    for (int off = 32; off; off >>= 1) racc += __shfl_down(racc, off, 64);
    if (lane == 0) wsum[wid] = racc;
    __syncthreads();
    if (threadIdx.x == 0) {
        float s = 0.0f;
        for (int w = 0; w < WPB; ++w) s += wsum[w];
        rsum[blockIdx.x] = s;
    }
    // ---- block 0: fold the 3072 proposals ----
    if (blockIdx.x == 0) {
        if (threadIdx.x == 0) { p_clp = 0; p_cln = 0; p_rg = 0; p_pos = 0; }
        if (threadIdx.x < 14) p_hn[threadIdx.x] = 0;
        __syncthreads();
        for (int t = threadIdx.x; t < B_ * A_ * M_; t += 1024) {
            int b = t / (A_ * M_);
            int a = (t / M_) % A_;
            const int* q = pidx + (size_t)t * 4;
            int c = q[0], w = q[1], h = q[2], lab = q[3];
            if (lab == -100) continue;
            if (lab < 0) { atomicAdd(&p_hn[-1 - lab], 1u); continue; }
            atomicAdd(&p_pos, 1u);
            const float* v = pm + (size_t)((((b * C_ + c) * W_ + w) * H_ + h) * A_ + a) * NCH;
            float clp = 0.0f, cln = 0.0f;
#pragma unroll
            for (int j = 0; j < NCLS; ++j) {
                float lg = v[3 + j];
                if (j == lab) clp = sp(-lg);
                else          cln += sp(lg);
            }
            float rg = 0.0f;
            const float* pr = preg + (size_t)t * 3;
#pragma unroll
            for (int j = 0; j < 3; ++j) {
                float d = tanhf(v[j]) - pr[j];
                float ad = fabsf(d);
                rg += (ad < 1.0f) ? 0.5f * d * d : ad - 0.5f;
            }
            atomicAdd(&p_clp, clp);
            atomicAdd(&p_cln, cln);
            atomicAdd(&p_rg, rg);
        }
        __syncthreads();
        if (threadIdx.x == 0) {
            facc[0] = p_clp; facc[1] = p_cln; facc[2] = p_rg;
            uacc[0] = p_pos;
        }
        if (threadIdx.x < 14) uacc[1 + threadIdx.x] = p_hn[threadIdx.x];
    }
}

// ==== KR: partials -> merged4 (non-atomic, 4-way split) ======================
__global__ __launch_bounds__(256)
void kr_reduce(const unsigned* __restrict__ partials,
               unsigned* __restrict__ merged4) {
    int slot = blockIdx.x * 256 + threadIdx.x;    // 0..4095
    int y = blockIdx.y;                           // 0..3
    unsigned a0 = 0, a1 = 0;
    int p0 = y * (KA_BLOCKS / 4), p1 = p0 + (KA_BLOCKS / 4);
    for (int p = p0; p < p1; ++p) {
        unsigned v = partials[(size_t)p * HSLOTS3 + slot];
        a0 += v & 0xFFFFu;
        a1 += v >> 16;
    }
    int bin = slot >> 3, pair = slot & 7;
    if (pair < 7) {
        merged4[y * (NHB * 16) + bin * 16 + 2 * pair] = a0;
        merged4[y * (NHB * 16) + bin * 16 + 2 * pair + 1] = a1;
    }
}

// ==== KB: per-class boundary; block 14 = regu total + done reset =============
__global__ __launch_bounds__(256)
void kb_bound(const unsigned* __restrict__ merged4,
              const float* __restrict__ rsum, const unsigned* __restrict__ uacc,
              int* __restrict__ bstar, unsigned* __restrict__ cntab,
              float* __restrict__ sumab, float* __restrict__ facc,
              unsigned long long* __restrict__ fine, unsigned* __restrict__ done) {
    int t = threadIdx.x;
    __shared__ unsigned cnt[NHB];
    __shared__ float ws2[256];
    if (blockIdx.x == 14) {
        if (t == 0) *done = 0u;
        ws2[t] = rsum[t] + rsum[t + 256];
        __syncthreads();
        for (int o = 128; o; o >>= 1) { if (t < o) ws2[t] += ws2[t + o]; __syncthreads(); }
        if (t == 0) facc[3] = ws2[0];
        return;
    }
    int cls = blockIdx.x;
    unsigned long long* fc = fine + (size_t)cls * NBIN_F;
    for (int s = t; s < NBIN_F; s += 256) fc[s] = 0ull;
    if (t == 0) sumab[cls] = 0.0f;
    unsigned k = uacc[1 + cls] * HARD_NUM;
    if (k == 0) { if (t == 0) bstar[cls] = -2; return; }
#pragma unroll
    for (int h = 0; h < 2; ++h) {
        int b = t + h * 256;
        unsigned c = 0;
#pragma unroll
        for (int y = 0; y < 4; ++y)
            c += merged4[y * (NHB * 16) + b * 16 + cls];
        cnt[b] = c;
    }
    __syncthreads();
    if (t == 0) {
        unsigned cum = 0; int bb = -1;
        for (int b = NHB - 1; b >= 0; --b) {
            unsigned c = cnt[b];
            if (cum + c >= k) { bb = b; break; }
            cum += c;
        }
        bstar[cls] = bb;            // -1 => select all candidates (fallback)
        cntab[cls] = cum;
    }
}

// ==== K3: candidates — sum above boundary + fine hist of boundary bin ========
__global__ __launch_bounds__(256)
void k3_cand(const unsigned* __restrict__ cand, const unsigned* __restrict__ nblk,
             const int* __restrict__ bstar, unsigned long long* __restrict__ fine,
             float* __restrict__ sumab, int seg_w) {
    __shared__ float csum[16];
    __shared__ int bst[16];
    int t = threadIdx.x;
    if (t < 16) { csum[t] = 0.0f; bst[t] = (t < 14) ? bstar[t] : -2; }
    __syncthreads();
    for (int w = 0; w < WPB; ++w) {
        unsigned wseg = blockIdx.x * WPB + w;
        const unsigned* gc = cand + (size_t)wseg * seg_w;
        unsigned n = nblk[wseg];
        for (unsigned i = t; i < n; i += 256) {
            unsigned e = gc[i];
            int cls = (int)(e & 15u);
            int b = bst[cls];
            if (b == -2) continue;
            unsigned ut = e & 0xFFFFFFF0u;
            unsigned key = ut | 0x80000000u;
            unsigned wb = (key >> KSHIFT) - HB0;
            if (wb > NHB - 1) wb = NHB - 1;
            float x = __uint_as_float(ut | 0x8u);
            if (b == -1 || (int)wb > b) {
                atomicAdd(&csum[cls], spf(x));
            } else if ((int)wb == b) {
                unsigned sub = (key >> (KSHIFT - SUBBITS)) & (NBIN_F - 1);
                unsigned long long pk = (1ull << 43)
                    | (unsigned long long)(spf(x) * 262144.0f + 0.5f);
                atomicAdd(&fine[(size_t)cls * NBIN_F + sub], pk);
            }
        }
    }
    __syncthreads();
    if (t < 14 && csum[t] != 0.0f) atomicAdd(&sumab[t], csum[t]);
}

// ==== K4: per-class resolve + last-block final combine =======================
__global__ __launch_bounds__(256)
void k4_resolve(const unsigned long long* __restrict__ fine,
                const unsigned* __restrict__ uacc, const int* __restrict__ bstar,
                const unsigned* __restrict__ cntab, const float* __restrict__ sumab,
                const float* __restrict__ facc, float* __restrict__ hnp,
                unsigned* __restrict__ done, float* __restrict__ out) {
    int cls = blockIdx.x, t = threadIdx.x;
    __shared__ unsigned ck[256];
    __shared__ float cs[256];
    __shared__ int lastflag;
    unsigned k = uacc[1 + cls] * HARD_NUM;
    if (k == 0) {
        if (t == 0) hnp[cls] = 0.0f;
    } else {
        int b = bstar[cls];
        if (b == -1) {
            if (t == 0) hnp[cls] = sumab[cls];
        } else {
            unsigned r = k - cntab[cls];
            const unsigned long long* fc = fine + (size_t)cls * NBIN_F;
            unsigned lc = 0; float ls = 0.0f;
            for (int j = 0; j < NBIN_F / 256; ++j) {
                unsigned long long v = fc[t * (NBIN_F / 256) + j];
                lc += (unsigned)(v >> 43);
                ls += (float)(v & ((1ull << 43) - 1)) * (1.0f / 262144.0f);
            }
            ck[t] = lc; cs[t] = ls;
            __syncthreads();
            if (t == 0) {
                unsigned cum = 0; float sa = sumab[cls];
                for (int ch = 255; ch >= 0; --ch) {
                    if (cum + ck[ch] >= r) {
                        unsigned c2 = cum;
                        for (int j = NBIN_F / 256 - 1; j >= 0; --j) {
                            unsigned long long v = fc[ch * (NBIN_F / 256) + j];
                            unsigned c = (unsigned)(v >> 43);
                            float s = (float)(v & ((1ull << 43) - 1)) * (1.0f / 262144.0f);
                            if (c2 + c >= r) {
                                unsigned rem = r - c2;
                                if (c > 0) sa += (float)rem * (s / (float)c);
                                break;
                            }
                            c2 += c; sa += s;
                        }
                        break;
                    }
                    cum += ck[ch]; sa += cs[ch];
                }
                hnp[cls] = sa;
            }
        }
    }
    __syncthreads();
    if (t == 0) {
        __threadfence();
        unsigned ticket = atomicAdd(done, 1u);
        lastflag = (ticket == NCLS - 1) ? 1 : 0;
    }
    __syncthreads();
    if (lastflag && t == 0) {
        __threadfence();
        float hn_sum = 0.0f; unsigned totk = 0;
        for (int j = 0; j < NCLS; ++j) { hn_sum += hnp[j]; totk += uacc[1 + j]; }
        totk *= HARD_NUM;
        float P = fmaxf((float)uacc[0], 1.0f);
        float hn = (totk > 0) ? (LAM_HNM * hn_sum / (float)totk) : 0.0f;
        out[0] = facc[0] / P
               + facc[1] / (P * (float)((NCLS - 1) * (NCLS - 1)))
               + hn
               + LAM_NOOBJ * facc[3] / (float)TOTAL
               + facc[2] / (3.0f * P);
    }
}

extern "C" void kernel_launch(void* const* d_in, const int* in_sizes, int n_in,
                              void* d_out, int out_size, void* d_ws, size_t ws_size,
                              hipStream_t stream) {
    const float* pm   = (const float*)d_in[0];
    const int*   pidx = (const int*)d_in[1];
    const float* preg = (const float*)d_in[2];
    float* out = (float*)d_out;
    char* ws = (char*)d_ws;

    float*    facc  = (float*)(ws + OFF_FACC);
    unsigned* uacc  = (unsigned*)(ws + OFF_UACC);
    int*      bstar = (int*)(ws + OFF_BSTAR);
    unsigned* cntab = (unsigned*)(ws + OFF_CNTAB);
    float*    sumab = (float*)(ws + OFF_SUMAB);
    float*    hnp   = (float*)(ws + OFF_HNP);
    unsigned* done  = (unsigned*)(ws + OFF_DONE);
    float*    rsum  = (float*)(ws + OFF_RSUM);
    unsigned* nblk  = (unsigned*)(ws + OFF_NBLK);
    unsigned long long* fine = (unsigned long long*)(ws + OFF_FINE);
    unsigned* merged4 = (unsigned*)(ws + OFF_MERGED);
    unsigned* partials = (unsigned*)(ws + OFF_PART);
    unsigned* cand = (unsigned*)(ws + OFF_CAND);

    long long remain = (long long)ws_size - (long long)OFF_CAND;
    int seg_w = (int)(remain / ((long long)NSEG * 4));
    if (seg_w > 2048) seg_w = 2048;
    seg_w &= ~63;
    if (seg_w < 512) seg_w = 512;   // expected ~430/wave; ws is large in practice

    k1_stream <<<KA_BLOCKS, 1024, 0, stream>>>(pm, pidx, preg, partials, cand,
                                               nblk, rsum, facc, uacc, seg_w);
    kr_reduce <<<dim3(HSLOTS3 / 256, 4), 256, 0, stream>>>(partials, merged4);
    kb_bound  <<<NCLS + 1, 256, 0, stream>>>(merged4, rsum, uacc, bstar, cntab,
                                             sumab, facc, fine, done);
    k3_cand   <<<KA_BLOCKS, 256, 0, stream>>>(cand, nblk, bstar, fine, sumab, seg_w);
    k4_resolve<<<NCLS, 256, 0, stream>>>(fine, uacc, bstar, cntab, sumab, facc,
                                         hnp, done, out);
}